// Round 19
// baseline (165.319 us; speedup 1.0000x reference)
//
#include <hip/hip_runtime.h>
#include <hip/hip_bf16.h>

constexpr int KST  = 12;
constexpr int NN   = 10;
constexpr int B    = 2;
constexpr int C    = 512;
constexpr int T    = 4096;
constexpr int BAND = 12;
constexpr int NCH  = C / 32;   // 16 chunks of 32

// Diagnostic repeat factors (output bit-correct: prep idempotent, others scaled)
constexpr int REP_P = 8;
constexpr int REP_C = 8;
constexpr int REP_B = 8;
constexpr int REP_G = 8;

typedef float f32x4  __attribute__((ext_vector_type(4)));
typedef short bf16x8 __attribute__((ext_vector_type(8)));
typedef unsigned short u16x8 __attribute__((ext_vector_type(8)));

__device__ __forceinline__ float logsig(float x) {
    return fminf(x, 0.0f) - log1pf(expf(-fabsf(x)));
}
__device__ __forceinline__ unsigned short f2bf(float f) {
    union { float f; unsigned u; } v; v.f = f;
    unsigned r = v.u + 0x7fff + ((v.u >> 16) & 1);   // RNE
    return (unsigned short)(r >> 16);
}

// ---------------------------------------------------------------------------
// prep_all (x REP_P idempotent):
//  [0, 1024)    : transpose-PACK, 2 tiles/block
//  [1024, 1280) : pack W ; zero out[0]
// ---------------------------------------------------------------------------
constexpr int PREP_TRANS_BLKS = 1024;
constexpr int PREP_GRID = PREP_TRANS_BLKS + (C * C) / (256 * 4);  // 1280

__global__ __launch_bounds__(256) void prep_all(
    const float* __restrict__ fc, const float* __restrict__ enc,
    const float* __restrict__ W,
    unsigned short* __restrict__ fcp, unsigned short* __restrict__ encp,
    unsigned short* __restrict__ Wp, float* __restrict__ out)
{
    __shared__ float lt[64][65];
    const int bid = blockIdx.x;
    const int tid = threadIdx.x;

    if (bid < PREP_TRANS_BLKS) {
        #pragma unroll 1
        for (int rep = 0; rep < REP_P; ++rep) {
            for (int r = 0; r < 2; ++r) {
                if (r | rep) __syncthreads();
                const int j   = bid * 2 + r;
                const int z   = j >> 9;
                const int rem = j & 511;
                const int t0  = (rem & 63) * 64;
                const int c0  = (rem >> 6) * 64;
                const float* src = (z < 2 ? fc : enc) + (size_t)(z & 1) * C * T;
                unsigned short* dst =
                    (z < 2 ? fcp : encp) + (size_t)(z & 1) * NCH * T * 32;

                const int tq = (tid & 15) * 4;
                const int cr = tid >> 4;
                #pragma unroll
                for (int p = 0; p < 4; ++p) {
                    const int c_row = p * 16 + cr;
                    const float4 v = *(const float4*)&src[(size_t)(c0 + c_row) * T + t0 + tq];
                    lt[tq + 0][c_row] = v.x;
                    lt[tq + 1][c_row] = v.y;
                    lt[tq + 2][c_row] = v.z;
                    lt[tq + 3][c_row] = v.w;
                }
                __syncthreads();

                const int t_row = tid >> 2;
                const int cq    = (tid & 3) * 16;
                u16x8 o0, o1;
                #pragma unroll
                for (int u = 0; u < 8; ++u) o0[u] = f2bf(lt[t_row][cq + u]);
                #pragma unroll
                for (int u = 0; u < 8; ++u) o1[u] = f2bf(lt[t_row][cq + 8 + u]);
                const int cg = c0 + cq;
                const int ks = cg >> 5;
                const int j0 = cg & 31;
                unsigned short* dp = dst + ((size_t)ks * T + t0 + t_row) * 32 + j0;
                *(u16x8*)dp       = o0;
                *(u16x8*)(dp + 8) = o1;
            }
        }
    } else {
        if (bid == PREP_TRANS_BLKS && tid == 0) out[0] = 0.0f;
        #pragma unroll 1
        for (int rep = 0; rep < REP_P; ++rep) {
            const int idx = ((bid - PREP_TRANS_BLKS) * 256 + tid) * 4;
            const int d = idx >> 9;
            const int k = idx & 511;
            const float4 v = *(const float4*)&W[idx];
            ushort4 o;
            o.x = f2bf(v.x); o.y = f2bf(v.y); o.z = f2bf(v.z); o.w = f2bf(v.w);
            *(ushort4*)&Wp[((size_t)(k >> 5) * C + d) * 32 + (k & 31)] = o;
        }
    }
}

// ---------------------------------------------------------------------------
// cgemm v4 (x REP_C accumulate, scaled): 128x128 LDS-staged double-buffered.
// ---------------------------------------------------------------------------
__global__ __launch_bounds__(256) void cgemm(
    const unsigned short* __restrict__ Wp, const unsigned short* __restrict__ fcp,
    const float* __restrict__ bias, unsigned short* __restrict__ cpk)
{
    const int bid = blockIdx.x;           // 256 blocks
    const int d0  = (bid >> 6) * 128;
    const int rem = bid & 63;
    const int t0  = (rem >> 1) * 128;
    const int b   = rem & 1;

    __shared__ unsigned short smem[4][128 * 40];

    const int tid  = threadIdx.x;
    const int lane = tid & 63;
    const int w    = tid >> 6;
    const int wt   = (w >> 1) * 64;
    const int wd   = (w & 1) * 64;
    const int l15  = lane & 15;
    const int l4   = lane >> 4;

    const unsigned short* Ag = fcp + (size_t)b * NCH * T * 32 + (size_t)t0 * 32;
    const unsigned short* Bg = Wp + (size_t)d0 * 32;

    const int srow  = tid >> 2;
    const int scol  = (tid & 3) * 8;
    const int sdst0 = srow * 40 + scol;
    const int sdst1 = (srow + 64) * 40 + scol;
    const int goff0 = tid * 8;
    const int goff1 = tid * 8 + 2048;

    f32x4 acc[4][4] = {};
    #pragma unroll 1
    for (int rep = 0; rep < REP_C; ++rep) {
        bf16x8 ar0 = *(const bf16x8*)(Ag + goff0);
        bf16x8 ar1 = *(const bf16x8*)(Ag + goff1);
        bf16x8 br0 = *(const bf16x8*)(Bg + goff0);
        bf16x8 br1 = *(const bf16x8*)(Bg + goff1);
        *(bf16x8*)&smem[0][sdst0] = ar0;
        *(bf16x8*)&smem[0][sdst1] = ar1;
        *(bf16x8*)&smem[1][sdst0] = br0;
        *(bf16x8*)&smem[1][sdst1] = br1;
        ar0 = *(const bf16x8*)(Ag + (size_t)1 * T * 32 + goff0);
        ar1 = *(const bf16x8*)(Ag + (size_t)1 * T * 32 + goff1);
        br0 = *(const bf16x8*)(Bg + (size_t)1 * C * 32 + goff0);
        br1 = *(const bf16x8*)(Bg + (size_t)1 * C * 32 + goff1);

        #pragma unroll 2
        for (int ks = 0; ks < NCH; ++ks) {
            __syncthreads();
            const int cur = ks & 1;
            bf16x8 afr[4], bfr[4];
            #pragma unroll
            for (int i = 0; i < 4; ++i)
                afr[i] = *(const bf16x8*)&smem[cur * 2][(wt + i * 16 + l15) * 40 + l4 * 8];
            #pragma unroll
            for (int j = 0; j < 4; ++j)
                bfr[j] = *(const bf16x8*)&smem[cur * 2 + 1][(wd + j * 16 + l15) * 40 + l4 * 8];

            if (ks + 1 < NCH) {
                *(bf16x8*)&smem[(cur ^ 1) * 2][sdst0]     = ar0;
                *(bf16x8*)&smem[(cur ^ 1) * 2][sdst1]     = ar1;
                *(bf16x8*)&smem[(cur ^ 1) * 2 + 1][sdst0] = br0;
                *(bf16x8*)&smem[(cur ^ 1) * 2 + 1][sdst1] = br1;
            }
            if (ks + 2 < NCH) {
                ar0 = *(const bf16x8*)(Ag + (size_t)(ks + 2) * T * 32 + goff0);
                ar1 = *(const bf16x8*)(Ag + (size_t)(ks + 2) * T * 32 + goff1);
                br0 = *(const bf16x8*)(Bg + (size_t)(ks + 2) * C * 32 + goff0);
                br1 = *(const bf16x8*)(Bg + (size_t)(ks + 2) * C * 32 + goff1);
            }
            #pragma unroll
            for (int i = 0; i < 4; ++i)
                #pragma unroll
                for (int j = 0; j < 4; ++j)
                    acc[i][j] = __builtin_amdgcn_mfma_f32_16x16x32_bf16(
                        afr[i], bfr[j], acc[i][j], 0, 0, 0);
        }
    }
    __syncthreads();

    constexpr float sc = 1.0f / REP_C;
    unsigned short* c_lds = &smem[0][0];
    #pragma unroll
    for (int j = 0; j < 4; ++j) {
        const int dcol = wd + j * 16 + l15;
        const float bv = bias[d0 + dcol];
        #pragma unroll
        for (int i = 0; i < 4; ++i) {
            const int trow = wt + i * 16 + l4 * 4;
            #pragma unroll
            for (int r = 0; r < 4; ++r)
                c_lds[(trow + r) * 136 + dcol] = f2bf(acc[i][j][r] * sc + bv);
        }
    }
    __syncthreads();

    {
        const int row  = tid >> 1;
        const int half = (tid & 1) * 64;
        #pragma unroll
        for (int q = 0; q < 2; ++q) {
            const int dloc = half + q * 32;
            const int ks2  = (d0 + dloc) >> 5;
            unsigned short* dp = cpk + (size_t)b * NCH * T * 32
                               + ((size_t)ks2 * T + t0 + row) * 32;
            const unsigned short* sp = &c_lds[row * 136 + dloc];
            *(u16x8*)(dp)      = *(const u16x8*)(sp);
            *(u16x8*)(dp + 8)  = *(const u16x8*)(sp + 8);
            *(u16x8*)(dp + 16) = *(const u16x8*)(sp + 16);
            *(u16x8*)(dp + 24) = *(const u16x8*)(sp + 24);
        }
    }
}

// ---------------------------------------------------------------------------
// band (x REP_B accumulate, scaled)
// ---------------------------------------------------------------------------
__global__ __launch_bounds__(512) void band_kernel(
    const unsigned short* __restrict__ encp, const unsigned short* __restrict__ cpk,
    float* __restrict__ negls, float* __restrict__ out)
{
    const int b  = blockIdx.y;
    const int n0 = blockIdx.x * 32;
    __shared__ float posred[8];

    const int tid  = threadIdx.x;
    const int lane = tid & 63;
    const int w    = tid >> 6;
    const int l15  = lane & 15;
    const int l4   = lane >> 4;

    const unsigned short* encpb = encp + (size_t)b * NCH * T * 32;
    const unsigned short* cpkb  = cpk  + (size_t)b * NCH * T * 32;

    const int i2 = w >> 1;
    const int j2 = w & 1;
    const int rg = i2 * 16 + l15;
    int ti;
    if (rg < 44) { ti = n0 + rg; ti = ti < T ? ti : T - 1; }
    else if (rg < 54) ti = rg - 44;
    else ti = 0;
    const unsigned short* A2p = encpb + (size_t)ti * 32 + l4 * 8;
    const unsigned short* B2p = cpkb + (size_t)(n0 + j2 * 16 + l15) * 32 + l4 * 8;

    f32x4 dacc = {};
    #pragma unroll 1
    for (int rep = 0; rep < REP_B; ++rep) {
        #pragma unroll 4
        for (int ks = 0; ks < NCH; ++ks) {
            const size_t o = (size_t)ks * T * 32;
            const bf16x8 a2 = *(const bf16x8*)(A2p + o);
            const bf16x8 b2 = *(const bf16x8*)(B2p + o);
            dacc = __builtin_amdgcn_mfma_f32_16x16x32_bf16(a2, b2, dacc, 0, 0, 0);
        }
    }
    constexpr float sc = 1.0f / REP_B;

    float pos = 0.0f;
    const int colr = j2 * 16 + l15;
    const int scol = n0 + colr;
    #pragma unroll
    for (int r = 0; r < 4; ++r) {
        const int row = i2 * 16 + l4 * 4 + r;
        const float vv = dacc[r] * sc;
        if (row < 44) {
            const int k = row - colr;
            if (k >= 0 && k < BAND && scol + k < T) pos += logsig(vv);
        } else if (row < 54) {
            negls[((size_t)b * NN + (row - 44)) * T + scol] = logsig(-vv);
        }
    }
    #pragma unroll
    for (int off = 32; off > 0; off >>= 1) pos += __shfl_down(pos, off, 64);
    if (lane == 0) posred[w] = pos;
    __syncthreads();
    if (tid == 0) {
        float tsum = 0.0f;
        #pragma unroll
        for (int q = 0; q < 8; ++q) tsum += posred[q];
        atomicAdd(out, tsum);
    }
}

// ---------------------------------------------------------------------------
// gather (x REP_G accumulate, scaled atomic)
// ---------------------------------------------------------------------------
__global__ __launch_bounds__(256) void gather_kernel(
    const int4* __restrict__ nidx4, const float* __restrict__ negls,
    float* __restrict__ out)
{
    constexpr int TOTAL4 = KST * T * NN / 4;   // 122880
    float local = 0.0f;
    #pragma unroll 1
    for (int rep = 0; rep < REP_G; ++rep) {
        for (int i4 = blockIdx.x * 256 + threadIdx.x; i4 < TOTAL4; i4 += 120 * 256) {
            const int4 vv = nidx4[i4];
            const int base = i4 * 4;
            const int idxs[4] = {vv.x, vv.y, vv.z, vv.w};
            #pragma unroll
            for (int e = 0; e < 4; ++e) {
                const int n = (base + e) % NN;
                local += negls[(size_t)n * T + idxs[e]]
                       + negls[(size_t)(NN + n) * T + idxs[e]];
            }
        }
    }
    #pragma unroll
    for (int off = 32; off > 0; off >>= 1) local += __shfl_down(local, off, 64);
    __shared__ float wsum[4];
    if ((threadIdx.x & 63) == 0) wsum[threadIdx.x >> 6] = local;
    __syncthreads();
    if (threadIdx.x == 0)
        atomicAdd(out, (float)NN * (wsum[0] + wsum[1] + wsum[2] + wsum[3])
                        * (1.0f / REP_G));
}

// ---------------------------------------------------------------------------
extern "C" void kernel_launch(void* const* d_in, const int* in_sizes, int n_in,
                              void* d_out, int out_size, void* d_ws, size_t ws_size,
                              hipStream_t stream)
{
    const float* enc  = (const float*)d_in[0];
    const float* fc   = (const float*)d_in[1];
    const float* W    = (const float*)d_in[2];
    const float* bias = (const float*)d_in[3];
    const int4*  nidx4 = (const int4*)d_in[4];
    float* out = (float*)d_out;

    unsigned short* fcp  = (unsigned short*)d_ws;                 // 8 MiB
    unsigned short* encp = fcp  + (size_t)B * NCH * T * 32;       // 8 MiB
    unsigned short* Wp   = encp + (size_t)B * NCH * T * 32;       // 512 KiB
    unsigned short* cpk  = Wp   + (size_t)C * C;                  // 8 MiB
    float* negls = (float*)(cpk + (size_t)B * NCH * T * 32);      // 320 KiB

    prep_all<<<PREP_GRID, 256, 0, stream>>>(fc, enc, W, fcp, encp, Wp, out);
    cgemm<<<256, 256, 0, stream>>>(Wp, fcp, bias, cpk);
    band_kernel<<<dim3(T / 32, B), 512, 0, stream>>>(encp, cpk, negls, out);
    gather_kernel<<<120, 256, 0, stream>>>(nidx4, negls, out);
}

// Round 20
// 51.033 us; speedup vs baseline: 3.2395x; 3.2395x over previous
//
#include <hip/hip_runtime.h>
#include <hip/hip_bf16.h>

constexpr int KST  = 12;
constexpr int NN   = 10;
constexpr int B    = 2;
constexpr int C    = 512;
constexpr int T    = 4096;
constexpr int BAND = 12;
constexpr int NCH  = C / 32;   // 16 chunks of 32
constexpr int NSL  = 16;       // histogram slices per n

typedef float f32x4  __attribute__((ext_vector_type(4)));
typedef short bf16x8 __attribute__((ext_vector_type(8)));
typedef unsigned short u16x8 __attribute__((ext_vector_type(8)));

__device__ __forceinline__ float logsig(float x) {
    return fminf(x, 0.0f) - log1pf(expf(-fabsf(x)));
}
__device__ __forceinline__ unsigned short f2bf(float f) {
    union { float f; unsigned u; } v; v.f = f;
    unsigned r = v.u + 0x7fff + ((v.u >> 16) & 1);   // RNE
    return (unsigned short)(r >> 16);
}

// ---------------------------------------------------------------------------
// prep_all:
//  [0, 1024)    : transpose-PACK, 2 tiles/block: X[b][c][t] -> Xp[b][c/32][t][c%32]
//  [1024, 1280) : pack W[d][k] -> Wp[k/32][d][k%32] ; zero out[0]
//  [1280, 1440) : histogram partials. Block (n, sl): LDS-hist of
//                 neg_idx[j*NN+n] for j in slice sl -> cnt16[n][s][sl].
//                 Race-free (private output slice), no global atomics.
// ---------------------------------------------------------------------------
constexpr int PREP_TRANS_BLKS = 1024;
constexpr int PREP_CAST_END   = PREP_TRANS_BLKS + (C * C) / (256 * 4); // 1280
constexpr int PREP_GRID       = PREP_CAST_END + NN * NSL;              // 1440

__global__ __launch_bounds__(256) void prep_all(
    const float* __restrict__ fc, const float* __restrict__ enc,
    const float* __restrict__ W, const int* __restrict__ nidx,
    unsigned short* __restrict__ fcp, unsigned short* __restrict__ encp,
    unsigned short* __restrict__ Wp, int* __restrict__ cnt16,
    float* __restrict__ out)
{
    __shared__ char smem[64 * 65 * 4];         // union: lt / hist
    float (*lt)[65] = (float (*)[65])smem;
    int* hist = (int*)smem;                    // 4096 bins (16 KB)

    const int bid = blockIdx.x;
    const int tid = threadIdx.x;

    if (bid < PREP_TRANS_BLKS) {
        #pragma unroll
        for (int r = 0; r < 2; ++r) {
            if (r) __syncthreads();
            const int j   = bid * 2 + r;       // 2048 tiles
            const int z   = j >> 9;            // 0,1=fc b0,b1; 2,3=enc b0,b1
            const int rem = j & 511;
            const int t0  = (rem & 63) * 64;
            const int c0  = (rem >> 6) * 64;
            const float* src = (z < 2 ? fc : enc) + (size_t)(z & 1) * C * T;
            unsigned short* dst =
                (z < 2 ? fcp : encp) + (size_t)(z & 1) * NCH * T * 32;

            const int tq = (tid & 15) * 4;
            const int cr = tid >> 4;
            #pragma unroll
            for (int p = 0; p < 4; ++p) {
                const int c_row = p * 16 + cr;
                const float4 v = *(const float4*)&src[(size_t)(c0 + c_row) * T + t0 + tq];
                lt[tq + 0][c_row] = v.x;
                lt[tq + 1][c_row] = v.y;
                lt[tq + 2][c_row] = v.z;
                lt[tq + 3][c_row] = v.w;
            }
            __syncthreads();

            const int t_row = tid >> 2;
            const int cq    = (tid & 3) * 16;
            u16x8 o0, o1;
            #pragma unroll
            for (int u = 0; u < 8; ++u) o0[u] = f2bf(lt[t_row][cq + u]);
            #pragma unroll
            for (int u = 0; u < 8; ++u) o1[u] = f2bf(lt[t_row][cq + 8 + u]);
            const int cg = c0 + cq;
            const int ks = cg >> 5;
            const int j0 = cg & 31;
            unsigned short* dp = dst + ((size_t)ks * T + t0 + t_row) * 32 + j0;
            *(u16x8*)dp       = o0;
            *(u16x8*)(dp + 8) = o1;
        }
    } else if (bid < PREP_CAST_END) {
        if (bid == PREP_TRANS_BLKS && tid == 0) out[0] = 0.0f;
        const int idx = ((bid - PREP_TRANS_BLKS) * 256 + tid) * 4;
        const int d = idx >> 9;
        const int k = idx & 511;
        const float4 v = *(const float4*)&W[idx];
        ushort4 o;
        o.x = f2bf(v.x); o.y = f2bf(v.y); o.z = f2bf(v.z); o.w = f2bf(v.w);
        *(ushort4*)&Wp[((size_t)(k >> 5) * C + d) * 32 + (k & 31)] = o;
    } else {
        // ---- histogram partial for (n, slice) ----
        const int h  = bid - PREP_CAST_END;    // 0..159
        const int n  = h >> 4;                 // 0..9
        const int sl = h & 15;                 // 0..15
        constexpr int SLICE = KST * T / NSL;   // 3072 j's per slice
        for (int s = tid; s < T; s += 256) hist[s] = 0;
        __syncthreads();
        const int jbase = sl * SLICE;
        for (int i = tid; i < SLICE; i += 256) {
            const int v = nidx[(size_t)(jbase + i) * NN + n];
            atomicAdd(&hist[v], 1);
        }
        __syncthreads();
        for (int s = tid; s < T; s += 256)
            cnt16[((size_t)n * T + s) * NSL + sl] = hist[s];
    }
}

// ---------------------------------------------------------------------------
// Fused GEMM + band + negative-fold (R12's verified fused body + cnt16 fold).
// Per (32-col s-tile, batch), 8 waves:
//  Stage A: c[d][s] = W @ fc + bias. Wave w: d in [w*64, (w+1)*64).
//    a-frags: Wp[ks][d-rows][32] (1KB contiguous), b-frags: fcp[ks][s-rows][32].
//  Epi  A : c frags + bias -> bf16 -> XOR-swizzled LDS c_t[s=32][d=512].
//  Stage B: D[64 x 32] = encp rows x c_t^T (contract over d).
//    rows 0..43 : diagonals k=row-col in [0,12) -> logsig -> pos sum
//    rows 44..53: n = row-44 -> pos += NN * (sum16 cnt16[n][scol][.]) * logsig(-v)
//  One atomicAdd(out) per block. No cpk, no negls, no gather kernel.
// Swizzle (c_t): elem (row, x) at byte row*1024 + (((x>>3)^(row&7))<<4)+(x&7)*2
// ---------------------------------------------------------------------------
__global__ __launch_bounds__(512) void fused_kernel(
    const unsigned short* __restrict__ Wp, const unsigned short* __restrict__ fcp,
    const unsigned short* __restrict__ encp, const float* __restrict__ bias,
    const int* __restrict__ cnt16, float* __restrict__ out)
{
    const int b  = blockIdx.y;
    const int n0 = blockIdx.x * 32;

    __shared__ unsigned short c_t[32 * 512];
    __shared__ float posred[8];

    const int tid  = threadIdx.x;
    const int lane = tid & 63;
    const int w    = tid >> 6;       // 0..7
    const int l15  = lane & 15;
    const int l4   = lane >> 4;      // 0..3
    const int mw   = w * 64;

    const unsigned short* fcpb  = fcp  + (size_t)b * NCH * T * 32;
    const unsigned short* encpb = encp + (size_t)b * NCH * T * 32;

    // ---------------- stage A: packed-fragment GEMM ----------------
    f32x4 acc[4][2] = {};
    const unsigned short* An  = Wp   + ((size_t)(mw + l15)) * 32 + l4 * 8;
    const unsigned short* Bn0 = fcpb + ((size_t)(n0 + l15)) * 32 + l4 * 8;
    const unsigned short* Bn1 = Bn0 + 16 * 32;

    #pragma unroll 4
    for (int ks = 0; ks < NCH; ++ks) {
        const size_t ao = (size_t)ks * C * 32;
        const size_t bo = (size_t)ks * T * 32;
        const bf16x8 b0 = *(const bf16x8*)(Bn0 + bo);
        const bf16x8 b1 = *(const bf16x8*)(Bn1 + bo);
        #pragma unroll
        for (int i = 0; i < 4; ++i) {
            const bf16x8 a = *(const bf16x8*)(An + ao + (size_t)i * 16 * 32);
            acc[i][0] = __builtin_amdgcn_mfma_f32_16x16x32_bf16(a, b0, acc[i][0], 0, 0, 0);
            acc[i][1] = __builtin_amdgcn_mfma_f32_16x16x32_bf16(a, b1, acc[i][1], 0, 0, 0);
        }
    }

    // ---------------- epilogue A: c frags -> swizzled c_t ----------------
    #pragma unroll
    for (int i = 0; i < 4; ++i) {
        const int mb = mw + i * 16 + l4 * 4;     // d base (mult of 4)
        const float4 bv = *(const float4*)&bias[mb];
        const int g = mb >> 3;
        #pragma unroll
        for (int j = 0; j < 2; ++j) {
            const int sp = j * 16 + l15;
            ushort4 u;
            u.x = f2bf(acc[i][j][0] + bv.x);
            u.y = f2bf(acc[i][j][1] + bv.y);
            u.z = f2bf(acc[i][j][2] + bv.z);
            u.w = f2bf(acc[i][j][3] + bv.w);
            const int off = sp * 1024 + ((g ^ (sp & 7)) << 4) + ((mb & 4) << 1);
            *(ushort4*)((char*)c_t + off) = u;
        }
    }
    __syncthreads();

    // ---------------- stage B: band MFMA ----------------
    const int i2 = w >> 1;               // 0..3 row-frag
    const int j2 = w & 1;                // 0..1 col-frag
    const int rg = i2 * 16 + l15;        // D row 0..63
    int ti;
    if (rg < 44) { ti = n0 + rg; ti = ti < T ? ti : T - 1; }
    else if (rg < 54) ti = rg - 44;
    else ti = 0;                          // unused rows
    const unsigned short* A2p = encpb + (size_t)ti * 32 + l4 * 8;
    const char* B2b = (const char*)c_t + (j2 * 16 + l15) * 1024;
    const int bx2 = l15 & 7;

    f32x4 dacc = {};
    #pragma unroll 4
    for (int ks = 0; ks < NCH; ++ks) {
        const bf16x8 a2 = *(const bf16x8*)(A2p + (size_t)ks * T * 32);
        const int ga = ks * 4 + l4;
        const bf16x8 b2 = *(const bf16x8*)(B2b + ((ga ^ bx2) << 4));
        dacc = __builtin_amdgcn_mfma_f32_16x16x32_bf16(a2, b2, dacc, 0, 0, 0);
    }

    // ---------------- epilogue B: logsig + cnt16 fold ----------------
    float pos = 0.0f;
    const int colr = j2 * 16 + l15;
    const int scol = n0 + colr;
    #pragma unroll
    for (int r = 0; r < 4; ++r) {
        const int row = i2 * 16 + l4 * 4 + r;
        const float vv = dacc[r];
        if (row < 44) {
            const int k = row - colr;
            if (k >= 0 && k < BAND && scol + k < T) pos += logsig(vv);
        } else if (row < 54) {
            const int4* cp = (const int4*)(cnt16
                + ((size_t)(row - 44) * T + scol) * NSL);
            int csum = 0;
            #pragma unroll
            for (int q = 0; q < 4; ++q) {
                const int4 cv = cp[q];
                csum += cv.x + cv.y + cv.z + cv.w;
            }
            if (csum) pos += (float)(NN * csum) * logsig(-vv);
        }
    }
    #pragma unroll
    for (int off = 32; off > 0; off >>= 1) pos += __shfl_down(pos, off, 64);
    if (lane == 0) posred[w] = pos;
    __syncthreads();
    if (tid == 0) {
        float tsum = 0.0f;
        #pragma unroll
        for (int q = 0; q < 8; ++q) tsum += posred[q];
        atomicAdd(out, tsum);
    }
}

// ---------------------------------------------------------------------------
extern "C" void kernel_launch(void* const* d_in, const int* in_sizes, int n_in,
                              void* d_out, int out_size, void* d_ws, size_t ws_size,
                              hipStream_t stream)
{
    const float* enc  = (const float*)d_in[0];
    const float* fc   = (const float*)d_in[1];
    const float* W    = (const float*)d_in[2];
    const float* bias = (const float*)d_in[3];
    const int*   nidx = (const int*)d_in[4];
    float* out = (float*)d_out;

    unsigned short* fcp  = (unsigned short*)d_ws;                 // 8 MiB
    unsigned short* encp = fcp  + (size_t)B * NCH * T * 32;       // 8 MiB
    unsigned short* Wp   = encp + (size_t)B * NCH * T * 32;       // 512 KiB
    int* cnt16 = (int*)(Wp + (size_t)C * C);                      // 2.5 MiB

    prep_all<<<PREP_GRID, 256, 0, stream>>>(fc, enc, W, nidx,
                                            fcp, encp, Wp, cnt16, out);
    fused_kernel<<<dim3(T / 32, B), 512, 0, stream>>>(Wp, fcp, encp, bias,
                                                      cnt16, out);
}

// Round 21
// 45.928 us; speedup vs baseline: 3.5995x; 1.1111x over previous
//
#include <hip/hip_runtime.h>
#include <hip/hip_bf16.h>

constexpr int KST  = 12;
constexpr int NN   = 10;
constexpr int B    = 2;
constexpr int C    = 512;
constexpr int T    = 4096;
constexpr int BAND = 12;
constexpr int NCH  = C / 32;   // 16 chunks of 32

typedef float f32x4  __attribute__((ext_vector_type(4)));
typedef short bf16x8 __attribute__((ext_vector_type(8)));
typedef unsigned short u16x8 __attribute__((ext_vector_type(8)));

__device__ __forceinline__ float logsig(float x) {
    return fminf(x, 0.0f) - log1pf(expf(-fabsf(x)));
}
__device__ __forceinline__ unsigned short f2bf(float f) {
    union { float f; unsigned u; } v; v.f = f;
    unsigned r = v.u + 0x7fff + ((v.u >> 16) & 1);   // RNE
    return (unsigned short)(r >> 16);
}

// ---------------------------------------------------------------------------
// prep_all:
//  [0, 1024)    : transpose-PACK, 2 tiles/block: X[b][c][t] -> Xp[b][c/32][t][c%32]
//  [1024, 1280) : pack W[d][k] -> Wp[k/32][d][k%32] ; zero out[0]
// ---------------------------------------------------------------------------
constexpr int PREP_TRANS_BLKS = 1024;
constexpr int PREP_GRID = PREP_TRANS_BLKS + (C * C) / (256 * 4);  // 1280

__global__ __launch_bounds__(256) void prep_all(
    const float* __restrict__ fc, const float* __restrict__ enc,
    const float* __restrict__ W,
    unsigned short* __restrict__ fcp, unsigned short* __restrict__ encp,
    unsigned short* __restrict__ Wp, float* __restrict__ out)
{
    __shared__ float lt[64][65];
    const int bid = blockIdx.x;
    const int tid = threadIdx.x;

    if (bid < PREP_TRANS_BLKS) {
        #pragma unroll
        for (int r = 0; r < 2; ++r) {
            if (r) __syncthreads();
            const int j   = bid * 2 + r;
            const int z   = j >> 9;
            const int rem = j & 511;
            const int t0  = (rem & 63) * 64;
            const int c0  = (rem >> 6) * 64;
            const float* src = (z < 2 ? fc : enc) + (size_t)(z & 1) * C * T;
            unsigned short* dst =
                (z < 2 ? fcp : encp) + (size_t)(z & 1) * NCH * T * 32;

            const int tq = (tid & 15) * 4;
            const int cr = tid >> 4;
            #pragma unroll
            for (int p = 0; p < 4; ++p) {
                const int c_row = p * 16 + cr;
                const float4 v = *(const float4*)&src[(size_t)(c0 + c_row) * T + t0 + tq];
                lt[tq + 0][c_row] = v.x;
                lt[tq + 1][c_row] = v.y;
                lt[tq + 2][c_row] = v.z;
                lt[tq + 3][c_row] = v.w;
            }
            __syncthreads();

            const int t_row = tid >> 2;
            const int cq    = (tid & 3) * 16;
            u16x8 o0, o1;
            #pragma unroll
            for (int u = 0; u < 8; ++u) o0[u] = f2bf(lt[t_row][cq + u]);
            #pragma unroll
            for (int u = 0; u < 8; ++u) o1[u] = f2bf(lt[t_row][cq + 8 + u]);
            const int cg = c0 + cq;
            const int ks = cg >> 5;
            const int j0 = cg & 31;
            unsigned short* dp = dst + ((size_t)ks * T + t0 + t_row) * 32 + j0;
            *(u16x8*)dp       = o0;
            *(u16x8*)(dp + 8) = o1;
        }
    } else {
        if (bid == PREP_TRANS_BLKS && tid == 0) out[0] = 0.0f;
        const int idx = ((bid - PREP_TRANS_BLKS) * 256 + tid) * 4;
        const int d = idx >> 9;
        const int k = idx & 511;
        const float4 v = *(const float4*)&W[idx];
        ushort4 o;
        o.x = f2bf(v.x); o.y = f2bf(v.y); o.z = f2bf(v.z); o.w = f2bf(v.w);
        *(ushort4*)&Wp[((size_t)(k >> 5) * C + d) * 32 + (k & 31)] = o;
    }
}

// ---------------------------------------------------------------------------
// cgemm v3 (R17, best measured): LDS-staged, double-buffered. cT[t][d]
// packed out as cpk[b][d/32][t][d%32]. Block 64t x 64d, 256 thr = 4 waves.
// Each 4KB packed k-chunk of A (fcp) and B (Wp) is loaded from L2 ONCE
// (256 thr x 16B, fully coalesced) into padded LDS (80B rows -> <=2-way
// banks), then both sharing waves read fragments via ds_read_b128.
// XCD-locality decode: panel = bid&127, d0 = bid>>7.
// ---------------------------------------------------------------------------
__global__ __launch_bounds__(256) void cgemm(
    const unsigned short* __restrict__ Wp, const unsigned short* __restrict__ fcp,
    const float* __restrict__ bias, unsigned short* __restrict__ cpk)
{
    const int bid   = blockIdx.x;
    const int panel = bid & 127;
    const int d0    = (bid >> 7) * 64;
    const int t0    = (panel & 63) * 64;
    const int b     = panel >> 6;

    __shared__ unsigned short A_lds[2][64 * 40];   // 80B rows (40 ushorts)
    __shared__ unsigned short B_lds[2][64 * 40];
    __shared__ unsigned short c_lds[64][68];

    const int tid  = threadIdx.x;
    const int lane = tid & 63;
    const int w    = tid >> 6;
    const int wt   = (w >> 1) * 32;
    const int wd   = (w & 1) * 32;
    const int l15  = lane & 15;
    const int l4   = lane >> 4;

    const unsigned short* Ag = fcp + (size_t)b * NCH * T * 32
                             + (size_t)t0 * 32 + tid * 8;
    const unsigned short* Bg = Wp + (size_t)d0 * 32 + tid * 8;

    const int sdst = (tid >> 2) * 40 + (tid & 3) * 8;

    bf16x8 ar = *(const bf16x8*)(Ag);
    bf16x8 br = *(const bf16x8*)(Bg);
    *(bf16x8*)&A_lds[0][sdst] = ar;
    *(bf16x8*)&B_lds[0][sdst] = br;
    ar = *(const bf16x8*)(Ag + (size_t)1 * T * 32);
    br = *(const bf16x8*)(Bg + (size_t)1 * C * 32);

    const int fa0 = (wt + l15) * 40 + l4 * 8;
    const int fa1 = (wt + 16 + l15) * 40 + l4 * 8;
    const int fb0 = (wd + l15) * 40 + l4 * 8;
    const int fb1 = (wd + 16 + l15) * 40 + l4 * 8;

    f32x4 acc[2][2] = {};
    #pragma unroll 4
    for (int ks = 0; ks < NCH; ++ks) {
        __syncthreads();
        const int cur = ks & 1;
        const bf16x8 a0 = *(const bf16x8*)&A_lds[cur][fa0];
        const bf16x8 a1 = *(const bf16x8*)&A_lds[cur][fa1];
        const bf16x8 b0 = *(const bf16x8*)&B_lds[cur][fb0];
        const bf16x8 b1 = *(const bf16x8*)&B_lds[cur][fb1];
        if (ks + 1 < NCH) {
            *(bf16x8*)&A_lds[cur ^ 1][sdst] = ar;
            *(bf16x8*)&B_lds[cur ^ 1][sdst] = br;
        }
        if (ks + 2 < NCH) {
            ar = *(const bf16x8*)(Ag + (size_t)(ks + 2) * T * 32);
            br = *(const bf16x8*)(Bg + (size_t)(ks + 2) * C * 32);
        }
        acc[0][0] = __builtin_amdgcn_mfma_f32_16x16x32_bf16(a0, b0, acc[0][0], 0, 0, 0);
        acc[0][1] = __builtin_amdgcn_mfma_f32_16x16x32_bf16(a0, b1, acc[0][1], 0, 0, 0);
        acc[1][0] = __builtin_amdgcn_mfma_f32_16x16x32_bf16(a1, b0, acc[1][0], 0, 0, 0);
        acc[1][1] = __builtin_amdgcn_mfma_f32_16x16x32_bf16(a1, b1, acc[1][1], 0, 0, 0);
    }

    #pragma unroll
    for (int j = 0; j < 2; ++j) {
        const int dcol = wd + j * 16 + l15;
        const float bv = bias[d0 + dcol];
        #pragma unroll
        for (int i = 0; i < 2; ++i) {
            const int trow = wt + i * 16 + l4 * 4;
            #pragma unroll
            for (int r = 0; r < 4; ++r)
                c_lds[trow + r][dcol] = f2bf(acc[i][j][r] + bv);
        }
    }
    __syncthreads();

    {
        const int t     = tid >> 2;
        const int piece = tid & 3;
        const int ks    = (d0 >> 5) + (piece >> 1);
        const int inner = (piece & 1) * 16;
        const u16x8 o0 = *(const u16x8*)&c_lds[t][piece * 16];
        const u16x8 o1 = *(const u16x8*)&c_lds[t][piece * 16 + 8];
        unsigned short* dp = cpk + (size_t)b * NCH * T * 32
                           + ((size_t)ks * T + t0 + t) * 32 + inner;
        *(u16x8*)dp       = o0;
        *(u16x8*)(dp + 8) = o1;
    }
}

// ---------------------------------------------------------------------------
// band (R14/R17): D[64 x 32] = enc-window rows x c cols over d.
// Grid (T/32, B) = 256 blocks, 512 thr = 8 waves.
// ---------------------------------------------------------------------------
__global__ __launch_bounds__(512) void band_kernel(
    const unsigned short* __restrict__ encp, const unsigned short* __restrict__ cpk,
    float* __restrict__ negls, float* __restrict__ out)
{
    const int b  = blockIdx.y;
    const int n0 = blockIdx.x * 32;
    __shared__ float posred[8];

    const int tid  = threadIdx.x;
    const int lane = tid & 63;
    const int w    = tid >> 6;
    const int l15  = lane & 15;
    const int l4   = lane >> 4;

    const unsigned short* encpb = encp + (size_t)b * NCH * T * 32;
    const unsigned short* cpkb  = cpk  + (size_t)b * NCH * T * 32;

    const int i2 = w >> 1;
    const int j2 = w & 1;
    const int rg = i2 * 16 + l15;
    int ti;
    if (rg < 44) { ti = n0 + rg; ti = ti < T ? ti : T - 1; }
    else if (rg < 54) ti = rg - 44;
    else ti = 0;
    const unsigned short* A2p = encpb + (size_t)ti * 32 + l4 * 8;
    const unsigned short* B2p = cpkb + (size_t)(n0 + j2 * 16 + l15) * 32 + l4 * 8;

    f32x4 dacc = {};
    #pragma unroll 4
    for (int ks = 0; ks < NCH; ++ks) {
        const size_t o = (size_t)ks * T * 32;
        const bf16x8 a2 = *(const bf16x8*)(A2p + o);
        const bf16x8 b2 = *(const bf16x8*)(B2p + o);
        dacc = __builtin_amdgcn_mfma_f32_16x16x32_bf16(a2, b2, dacc, 0, 0, 0);
    }

    float pos = 0.0f;
    const int colr = j2 * 16 + l15;
    const int scol = n0 + colr;
    #pragma unroll
    for (int r = 0; r < 4; ++r) {
        const int row = i2 * 16 + l4 * 4 + r;
        const float vv = dacc[r];
        if (row < 44) {
            const int k = row - colr;
            if (k >= 0 && k < BAND && scol + k < T) pos += logsig(vv);
        } else if (row < 54) {
            negls[((size_t)b * NN + (row - 44)) * T + scol] = logsig(-vv);
        }
    }
    #pragma unroll
    for (int off = 32; off > 0; off >>= 1) pos += __shfl_down(pos, off, 64);
    if (lane == 0) posred[w] = pos;
    __syncthreads();
    if (tid == 0) {
        float tsum = 0.0f;
        #pragma unroll
        for (int q = 0; q < 8; ++q) tsum += posred[q];
        atomicAdd(out, tsum);
    }
}

// ---------------------------------------------------------------------------
// gather: out += NN * sum logsig(-cont[b,n,idx]). 120 blocks x 4 iters.
// ---------------------------------------------------------------------------
__global__ __launch_bounds__(256) void gather_kernel(
    const int4* __restrict__ nidx4, const float* __restrict__ negls,
    float* __restrict__ out)
{
    constexpr int TOTAL4 = KST * T * NN / 4;   // 122880
    float local = 0.0f;
    for (int i4 = blockIdx.x * 256 + threadIdx.x; i4 < TOTAL4; i4 += 120 * 256) {
        const int4 vv = nidx4[i4];
        const int base = i4 * 4;
        const int idxs[4] = {vv.x, vv.y, vv.z, vv.w};
        #pragma unroll
        for (int e = 0; e < 4; ++e) {
            const int n = (base + e) % NN;
            local += negls[(size_t)n * T + idxs[e]]
                   + negls[(size_t)(NN + n) * T + idxs[e]];
        }
    }
    #pragma unroll
    for (int off = 32; off > 0; off >>= 1) local += __shfl_down(local, off, 64);
    __shared__ float wsum[4];
    if ((threadIdx.x & 63) == 0) wsum[threadIdx.x >> 6] = local;
    __syncthreads();
    if (threadIdx.x == 0)
        atomicAdd(out, (float)NN * (wsum[0] + wsum[1] + wsum[2] + wsum[3]));
}

// ---------------------------------------------------------------------------
extern "C" void kernel_launch(void* const* d_in, const int* in_sizes, int n_in,
                              void* d_out, int out_size, void* d_ws, size_t ws_size,
                              hipStream_t stream)
{
    const float* enc  = (const float*)d_in[0];
    const float* fc   = (const float*)d_in[1];
    const float* W    = (const float*)d_in[2];
    const float* bias = (const float*)d_in[3];
    const int4*  nidx4 = (const int4*)d_in[4];
    float* out = (float*)d_out;

    unsigned short* fcp  = (unsigned short*)d_ws;                 // 8 MiB
    unsigned short* encp = fcp  + (size_t)B * NCH * T * 32;       // 8 MiB
    unsigned short* Wp   = encp + (size_t)B * NCH * T * 32;       // 512 KiB
    unsigned short* cpk  = Wp   + (size_t)C * C;                  // 8 MiB
    float* negls = (float*)(cpk + (size_t)B * NCH * T * 32);      // 320 KiB

    prep_all<<<PREP_GRID, 256, 0, stream>>>(fc, enc, W, fcp, encp, Wp, out);
    cgemm<<<1024, 256, 0, stream>>>(Wp, fcp, bias, cpk);
    band_kernel<<<dim3(T / 32, B), 512, 0, stream>>>(encp, cpk, negls, out);
    gather_kernel<<<120, 256, 0, stream>>>(nidx4, negls, out);
}